// Round 4
// baseline (134.085 us; speedup 1.0000x reference)
//
#include <hip/hip_runtime.h>
#include <hip/hip_fp16.h>

// StableTTLayer TT forward, B=131072. Round 4: pair-table contraction.
// Only 64^2=4096 (col,col) pairs exist per adjacent core pair vs 131072
// samples -> precompute T01 (core0*mid0), T12 (mid1*mid2), T34 (mid3*mid4),
// TL (mid5*core_last) once per call; main kernel does 8B + 2x2KB + 16B reads
// per sample instead of 12.3KB. All tables baked with x256 scale per stage
// (v stays ~0.1 in fp16); undo 2^-32 at the end (exact).
// Norm stabilization cancels exactly -> skipped (validated R1-R3).

#define B_TOTAL 131072
#define NDIM 64
#define RANK 32

typedef _Float16 half8_t  __attribute__((ext_vector_type(8)));
typedef _Float16 half2_t  __attribute__((ext_vector_type(2)));
typedef float    float4_t __attribute__((ext_vector_type(4)));
union H2 { unsigned int u; half2_t h; __half2 hh; };

#if defined(__has_builtin)
#if __has_builtin(__builtin_amdgcn_fdot2)
#define HAVE_FDOT2 1
#endif
#endif

// ---------------- K1: small tables -----------------------------------------
// id < 131072: T01[(c0*64+c1)*32+s] = 256 * sum_r core0[c0,r]*mid0[r,c1,s]
// else:        TL [(c6*64+c7)*32+r] = 256 * sum_s mid5[r,c6,s]*lastc[s,c7]
__global__ __launch_bounds__(256) void build_small(
    const float* __restrict__ core0, const float* __restrict__ mid,
    const float* __restrict__ lastc,
    __half* __restrict__ T01, float* __restrict__ TL)
{
    const int id = blockIdx.x * 256 + threadIdx.x;   // 262144 total
    if (id < 131072) {
        const int s = id & 31, c1 = (id >> 5) & 63, c0 = id >> 11;
        float acc = 0.f;
        #pragma unroll
        for (int r = 0; r < 32; ++r)
            acc = fmaf(core0[c0 * 32 + r], mid[(r * 64 + c1) * 32 + s], acc);
        T01[(c0 * 64 + c1) * 32 + s] = __float2half(acc * 256.0f);
    } else {
        const int id2 = id - 131072;
        const int c7 = id2 & 63, c6 = (id2 >> 6) & 63, r = id2 >> 12;
        const float* m5 = mid + 5 * 65536;
        float acc = 0.f;
        #pragma unroll
        for (int s = 0; s < 32; ++s)
            acc = fmaf(m5[(r * 64 + c6) * 32 + s], lastc[s * 64 + c7], acc);
        TL[(c6 * 64 + c7) * 32 + r] = acc * 256.0f;
    }
}

// ---------------- K2: pair tables via MFMA ----------------------------------
// One wave per (tau, cA, cB): C(32x32) = A(32x32) @ B(32x32), A=mid[1+2tau]
// slice cA, B=mid[2+2tau] slice cB. Output packed pk layout:
// out[(r2)*32 + s] = half2(256*C[2r2][s], 256*C[2r2+1][s]).
__global__ __launch_bounds__(256) void build_pairs(
    const float* __restrict__ mid,
    __half2* __restrict__ T12, __half2* __restrict__ T34)
{
    const int w    = blockIdx.x * 4 + (threadIdx.x >> 6);   // 0..8191
    const int lane = threadIdx.x & 63;
    const int tau  = w >> 12;
    const int pair = w & 4095;
    const int cA = pair >> 6, cB = pair & 63;
    const float* m1 = mid + (1 + 2 * tau) * 65536;
    const float* m2 = mid + (2 + 2 * tau) * 65536;
    __half2* out = (tau ? T34 : T12) + pair * 512;

    const int q = lane >> 4, li = lane & 15;
    const int k0 = q * 8;

    half8_t A[2], Bf[2];
    #pragma unroll
    for (int t = 0; t < 2; ++t) {
        const int m = t * 16 + li;                 // A row / B col
        const float* ap = m1 + (m * 64 + cA) * 32 + k0;
        #pragma unroll
        for (int j = 0; j < 8; ++j) A[t][j] = (_Float16)ap[j];
        #pragma unroll
        for (int j = 0; j < 8; ++j) Bf[t][j] = (_Float16)m2[((k0 + j) * 64 + cB) * 32 + m];
    }
    #pragma unroll
    for (int mi = 0; mi < 2; ++mi) {
        #pragma unroll
        for (int ni = 0; ni < 2; ++ni) {
            float4_t d = {0.f, 0.f, 0.f, 0.f};
            d = __builtin_amdgcn_mfma_f32_16x16x32_f16(A[mi], Bf[ni], d, 0, 0, 0);
            // D elem: row = mi*16 + q*4 + reg, col = ni*16 + li
            const int col = ni * 16 + li;
            const int r2  = (mi * 16 + q * 4) >> 1;        // row pairs
            H2 p0, p1;
            p0.hh = __float22half2_rn(make_float2(d[0] * 256.f, d[1] * 256.f));
            p1.hh = __float22half2_rn(make_float2(d[2] * 256.f, d[3] * 256.f));
            out[(r2 + 0) * 32 + col] = p0.hh;
            out[(r2 + 1) * 32 + col] = p1.hh;
        }
    }
}

// ---------------- K3: main — 8 lanes per sample -----------------------------
__global__ __launch_bounds__(256) void tt_main(
    const int* __restrict__ idx, const __half* __restrict__ T01,
    const __half2* __restrict__ T12, const __half2* __restrict__ T34,
    const float* __restrict__ TL, float* __restrict__ out)
{
    const int tid   = blockIdx.x * 256 + threadIdx.x;
    const int b     = tid >> 3;
    const int g     = tid & 7;
    const int lane  = threadIdx.x & 63;
    const int gbase = lane & ~7;

    int my = idx[tid];                    // coalesced: idx[b*8+g]
    my = min(max(my, 0), NDIM - 1);
    const int c0 = __shfl(my, gbase + 0), c1 = __shfl(my, gbase + 1);
    const int c2 = __shfl(my, gbase + 2), c3 = __shfl(my, gbase + 3);
    const int c4 = __shfl(my, gbase + 4), c5 = __shfl(my, gbase + 5);
    const int c6 = __shfl(my, gbase + 6), c7 = __shfl(my, gbase + 7);

    // v init: 8B from T01
    const uint2 q0 = *reinterpret_cast<const uint2*>(T01 + (c0 * 64 + c1) * 32 + 4 * g);
    H2 v01, v23; v01.u = q0.x; v23.u = q0.y;

    // two pair-steps
    #pragma unroll
    for (int t = 0; t < 2; ++t) {
        const __half2* M = (t == 0) ? (T12 + (c2 * 64 + c3) * 512 + 4 * g)
                                    : (T34 + (c4 * 64 + c5) * 512 + 4 * g);
        float a0 = 0.f, a1 = 0.f, a2 = 0.f, a3 = 0.f;
        #pragma unroll
        for (int r2 = 0; r2 < 16; ++r2) {
            H2 vp; vp.u = __shfl((r2 & 1) ? v23.u : v01.u, gbase + (r2 >> 1));
            const uint4 mr = *reinterpret_cast<const uint4*>(M + r2 * 32);
            H2 m0, m1, m2, m3; m0.u = mr.x; m1.u = mr.y; m2.u = mr.z; m3.u = mr.w;
#ifdef HAVE_FDOT2
            a0 = __builtin_amdgcn_fdot2(vp.h, m0.h, a0, false);
            a1 = __builtin_amdgcn_fdot2(vp.h, m1.h, a1, false);
            a2 = __builtin_amdgcn_fdot2(vp.h, m2.h, a2, false);
            a3 = __builtin_amdgcn_fdot2(vp.h, m3.h, a3, false);
#else
            const float vl = __low2float(vp.hh), vh = __high2float(vp.hh);
            a0 = fmaf(vl, __low2float(m0.hh), fmaf(vh, __high2float(m0.hh), a0));
            a1 = fmaf(vl, __low2float(m1.hh), fmaf(vh, __high2float(m1.hh), a1));
            a2 = fmaf(vl, __low2float(m2.hh), fmaf(vh, __high2float(m2.hh), a2));
            a3 = fmaf(vl, __low2float(m3.hh), fmaf(vh, __high2float(m3.hh), a3));
#endif
        }
        v01.hh = __float22half2_rn(make_float2(a0, a1));
        v23.hh = __float22half2_rn(make_float2(a2, a3));
    }

    // final: 16B fp32 from TL, dot + 8-lane reduce, undo 2^32 scale
    const float4 L = *reinterpret_cast<const float4*>(TL + (c6 * 64 + c7) * 32 + 4 * g);
    float o = 0.f;
    o = fmaf(__low2float(v01.hh),  L.x, o);
    o = fmaf(__high2float(v01.hh), L.y, o);
    o = fmaf(__low2float(v23.hh),  L.z, o);
    o = fmaf(__high2float(v23.hh), L.w, o);
    o += __shfl_xor(o, 1);
    o += __shfl_xor(o, 2);
    o += __shfl_xor(o, 4);
    if (g == 0) out[b] = o * 2.3283064365386963e-10f;   // 2^-32
}

// ---------------- Fallback (R3 path) if ws too small ------------------------
__global__ __launch_bounds__(256) void tt_repack(
    const float* __restrict__ mid, const float* __restrict__ lastc,
    __half2* __restrict__ pk, float* __restrict__ lastT)
{
    const int i = blockIdx.x * 256 + threadIdx.x;
    const int s = i & 31, r2 = (i >> 5) & 15, c = (i >> 9) & 63, t = i >> 15;
    const float a = mid[(((t * 32 + 2 * r2 + 0) * 64) + c) * 32 + s];
    const float b = mid[(((t * 32 + 2 * r2 + 1) * 64) + c) * 32 + s];
    pk[i] = __float22half2_rn(make_float2(a, b));
    if (i < NDIM * RANK) {
        const int r = i & 31, cc = i >> 5;
        lastT[cc * RANK + r] = lastc[r * NDIM + cc];
    }
}

__global__ __launch_bounds__(256) void tt_forward_h(
    const int* __restrict__ idx, const float* __restrict__ core0,
    const __half2* __restrict__ pk, const float* __restrict__ lastT,
    float* __restrict__ out)
{
    const int tid = blockIdx.x * 256 + threadIdx.x;
    const int b = tid >> 3, g = tid & 7;
    const int lane = threadIdx.x & 63, gbase = lane & ~7;
    int my = idx[tid]; my = min(max(my, 0), NDIM - 1);
    const int c0 = __shfl(my, gbase + 0);
    const float4 f0 = *reinterpret_cast<const float4*>(core0 + c0 * RANK + 4 * g);
    H2 v01, v23;
    v01.hh = __float22half2_rn(make_float2(f0.x, f0.y));
    v23.hh = __float22half2_rn(make_float2(f0.z, f0.w));
    #pragma unroll
    for (int t = 0; t < 6; ++t) {
        const int cc = __shfl(my, gbase + 1 + t);
        const __half2* M = pk + ((t * 64 + cc) * 16) * 32 + 4 * g;
        float a0 = 0.f, a1 = 0.f, a2 = 0.f, a3 = 0.f;
        #pragma unroll
        for (int r2 = 0; r2 < 16; ++r2) {
            H2 vp; vp.u = __shfl((r2 & 1) ? v23.u : v01.u, gbase + (r2 >> 1));
            const uint4 mr = *reinterpret_cast<const uint4*>(M + r2 * 32);
            H2 m0, m1, m2, m3; m0.u = mr.x; m1.u = mr.y; m2.u = mr.z; m3.u = mr.w;
#ifdef HAVE_FDOT2
            a0 = __builtin_amdgcn_fdot2(vp.h, m0.h, a0, false);
            a1 = __builtin_amdgcn_fdot2(vp.h, m1.h, a1, false);
            a2 = __builtin_amdgcn_fdot2(vp.h, m2.h, a2, false);
            a3 = __builtin_amdgcn_fdot2(vp.h, m3.h, a3, false);
#else
            const float vl = __low2float(vp.hh), vh = __high2float(vp.hh);
            a0 = fmaf(vl, __low2float(m0.hh), fmaf(vh, __high2float(m0.hh), a0));
            a1 = fmaf(vl, __low2float(m1.hh), fmaf(vh, __high2float(m1.hh), a1));
            a2 = fmaf(vl, __low2float(m2.hh), fmaf(vh, __high2float(m2.hh), a2));
            a3 = fmaf(vl, __low2float(m3.hh), fmaf(vh, __high2float(m3.hh), a3));
#endif
        }
        v01.hh = __float22half2_rn(make_float2(a0 * 16.f, a1 * 16.f));
        v23.hh = __float22half2_rn(make_float2(a2 * 16.f, a3 * 16.f));
    }
    const int c7 = __shfl(my, gbase + 7);
    const float4 L = *reinterpret_cast<const float4*>(lastT + c7 * RANK + 4 * g);
    float o = 0.f;
    o = fmaf(__low2float(v01.hh),  L.x, o);
    o = fmaf(__high2float(v01.hh), L.y, o);
    o = fmaf(__low2float(v23.hh),  L.z, o);
    o = fmaf(__high2float(v23.hh), L.w, o);
    o += __shfl_xor(o, 1); o += __shfl_xor(o, 2); o += __shfl_xor(o, 4);
    if (g == 0) out[b] = o * (1.0f / 16777216.0f);
}

// ---------------- host ------------------------------------------------------
#define T12_OFF  0u
#define T34_OFF  8388608u
#define T01_OFF  16777216u
#define TL_OFF   17039360u
#define WS_NEED  (17039360u + 524288u)

extern "C" void kernel_launch(void* const* d_in, const int* in_sizes, int n_in,
                              void* d_out, int out_size, void* d_ws, size_t ws_size,
                              hipStream_t stream) {
    const int*   idx   = (const int*)d_in[0];    // (B, 8) int32
    const float* core0 = (const float*)d_in[1];  // (1, 64, 32)
    const float* mid   = (const float*)d_in[2];  // (6, 32, 64, 32)
    const float* lastc = (const float*)d_in[3];  // (32, 64, 1)
    float* out = (float*)d_out;

    if (ws_size >= WS_NEED) {
        __half2* T12 = (__half2*)((char*)d_ws + T12_OFF);
        __half2* T34 = (__half2*)((char*)d_ws + T34_OFF);
        __half*  T01 = (__half*)((char*)d_ws + T01_OFF);
        float*   TL  = (float*)((char*)d_ws + TL_OFF);
        hipLaunchKernelGGL(build_small, dim3(262144 / 256), dim3(256), 0, stream,
                           core0, mid, lastc, T01, TL);
        hipLaunchKernelGGL(build_pairs, dim3(2048), dim3(256), 0, stream,
                           mid, T12, T34);
        hipLaunchKernelGGL(tt_main, dim3((B_TOTAL * 8) / 256), dim3(256), 0, stream,
                           idx, T01, T12, T34, TL, out);
    } else {
        // fallback: R3 structure (needs ~795KB ws)
        __half2* pk    = (__half2*)d_ws;
        float*   lastT = (float*)((char*)d_ws + 786432);
        hipLaunchKernelGGL(tt_repack, dim3(196608 / 256), dim3(256), 0, stream,
                           mid, lastc, pk, lastT);
        hipLaunchKernelGGL(tt_forward_h, dim3((B_TOTAL * 8) / 256), dim3(256), 0, stream,
                           idx, core0, pk, lastT, out);
    }
}

// Round 5
// 97.957 us; speedup vs baseline: 1.3688x; 1.3688x over previous
//
#include <hip/hip_runtime.h>
#include <hip/hip_fp16.h>

// StableTTLayer TT forward, B=131072. Round 5.
// R4 post-mortem: 16.8 MB pair tables thrash per-XCD L2 (4 MB) -> 214 MB L3
// traffic at 3.6 TB/s. R5 keeps the validated tiny tables (T01 256KB collapses
// stages 0-1; TL 512KB collapses stages 6-7) and gathers the 4 middle stages
// from a 1 MB fp16 pk table (R3's proven inner loop). Working set 1.75 MB ->
// fully L2-resident. Per-sample traffic 8.4 KB (vs R3 12.3, R4 4.2-but-L3).
// Scales baked in tables: 256 * 16^4 * 256 = 2^32, undone exactly at the end.
// Norm stabilization cancels exactly -> skipped (validated R1-R4).

#define B_TOTAL 131072
#define NDIM 64
#define RANK 32

typedef _Float16 half2_t __attribute__((ext_vector_type(2)));
union H2 { unsigned int u; half2_t h; __half2 hh; };

#if defined(__has_builtin)
#if __has_builtin(__builtin_amdgcn_fdot2)
#define HAVE_FDOT2 1
#endif
#endif

// ---------------- K1: build all tables --------------------------------------
// ids [0,131072):       PK   (mid1..mid4 fp16 pairs, x16 baked)
// ids [131072,262144):  T01  (core0 . mid0, fp16, x256 baked)
// ids [262144,393216):  TL   (mid5 . core_last, fp32, x256 baked)
__global__ __launch_bounds__(256) void build_tables(
    const float* __restrict__ core0, const float* __restrict__ mid,
    const float* __restrict__ lastc,
    __half2* __restrict__ PK, __half* __restrict__ T01, float* __restrict__ TL)
{
    const int id = blockIdx.x * 256 + threadIdx.x;
    if (id < 131072) {
        // PK[((tt*64+c)*16+r2)*32+s] = half2(16*m[2r2], 16*m[2r2+1]),
        // m = mid[1+tt][r][c][s]
        const int s = id & 31, r2 = (id >> 5) & 15, c = (id >> 9) & 63, tt = id >> 15;
        const int t = 1 + tt;
        const float a = mid[((t * 32 + 2 * r2 + 0) * 64 + c) * 32 + s];
        const float b = mid[((t * 32 + 2 * r2 + 1) * 64 + c) * 32 + s];
        H2 p; p.hh = __float22half2_rn(make_float2(a * 16.f, b * 16.f));
        PK[id] = p.hh;   // id == ((tt*64+c)*16+r2)*32+s by construction
    } else if (id < 262144) {
        const int i2 = id - 131072;
        const int s = i2 & 31, c1 = (i2 >> 5) & 63, c0 = i2 >> 11;
        float acc = 0.f;
        #pragma unroll
        for (int r = 0; r < 32; ++r)
            acc = fmaf(core0[c0 * 32 + r], mid[(r * 64 + c1) * 32 + s], acc);
        T01[(c0 * 64 + c1) * 32 + s] = __float2half(acc * 256.0f);
    } else {
        const int i3 = id - 262144;
        const int c7 = i3 & 63, c6 = (i3 >> 6) & 63, r = i3 >> 12;
        const float* m5 = mid + 5 * 65536;
        float acc = 0.f;
        #pragma unroll
        for (int s = 0; s < 32; ++s)
            acc = fmaf(m5[(r * 64 + c6) * 32 + s], lastc[s * 64 + c7], acc);
        TL[(c6 * 64 + c7) * 32 + r] = acc * 256.0f;
    }
}

// ---------------- K2: main — 8 lanes per sample ------------------------------
__global__ __launch_bounds__(256) void tt_main(
    const int* __restrict__ idx, const __half* __restrict__ T01,
    const __half2* __restrict__ PK, const float* __restrict__ TL,
    float* __restrict__ out)
{
    const int tid   = blockIdx.x * 256 + threadIdx.x;
    const int b     = tid >> 3;
    const int g     = tid & 7;
    const int lane  = threadIdx.x & 63;
    const int gbase = lane & ~7;

    int my = idx[tid];                    // coalesced: idx[b*8+g]
    my = min(max(my, 0), NDIM - 1);
    const int c0 = __shfl(my, gbase + 0), c1 = __shfl(my, gbase + 1);
    const int c6 = __shfl(my, gbase + 6), c7 = __shfl(my, gbase + 7);

    // v init: 8B per lane from T01 (x256 true value, fp16)
    const uint2 q0 = *reinterpret_cast<const uint2*>(T01 + (c0 * 64 + c1) * 32 + 4 * g);
    H2 v01, v23; v01.u = q0.x; v23.u = q0.y;

    // 4 middle matvecs vs PK[tt] (x16 baked each)
    #pragma unroll
    for (int tt = 0; tt < 4; ++tt) {
        const int cc = __shfl(my, gbase + 2 + tt);
        const __half2* M = PK + ((tt * 64 + cc) * 16) * 32 + 4 * g;
        float a0 = 0.f, a1 = 0.f, a2 = 0.f, a3 = 0.f;
        #pragma unroll
        for (int r2 = 0; r2 < 16; ++r2) {
            H2 vp; vp.u = __shfl((r2 & 1) ? v23.u : v01.u, gbase + (r2 >> 1));
            const uint4 mr = *reinterpret_cast<const uint4*>(M + r2 * 32);
            H2 m0, m1, m2, m3; m0.u = mr.x; m1.u = mr.y; m2.u = mr.z; m3.u = mr.w;
#ifdef HAVE_FDOT2
            a0 = __builtin_amdgcn_fdot2(vp.h, m0.h, a0, false);
            a1 = __builtin_amdgcn_fdot2(vp.h, m1.h, a1, false);
            a2 = __builtin_amdgcn_fdot2(vp.h, m2.h, a2, false);
            a3 = __builtin_amdgcn_fdot2(vp.h, m3.h, a3, false);
#else
            const float vl = __low2float(vp.hh), vh = __high2float(vp.hh);
            a0 = fmaf(vl, __low2float(m0.hh), fmaf(vh, __high2float(m0.hh), a0));
            a1 = fmaf(vl, __low2float(m1.hh), fmaf(vh, __high2float(m1.hh), a1));
            a2 = fmaf(vl, __low2float(m2.hh), fmaf(vh, __high2float(m2.hh), a2));
            a3 = fmaf(vl, __low2float(m3.hh), fmaf(vh, __high2float(m3.hh), a3));
#endif
        }
        v01.hh = __float22half2_rn(make_float2(a0, a1));
        v23.hh = __float22half2_rn(make_float2(a2, a3));
    }

    // final: 16B fp32 from TL (x256), dot + 8-lane reduce, undo 2^32
    const float4 L = *reinterpret_cast<const float4*>(TL + (c6 * 64 + c7) * 32 + 4 * g);
    float o = 0.f;
    o = fmaf(__low2float(v01.hh),  L.x, o);
    o = fmaf(__high2float(v01.hh), L.y, o);
    o = fmaf(__low2float(v23.hh),  L.z, o);
    o = fmaf(__high2float(v23.hh), L.w, o);
    o += __shfl_xor(o, 1);
    o += __shfl_xor(o, 2);
    o += __shfl_xor(o, 4);
    if (g == 0) out[b] = o * 2.3283064365386963e-10f;   // 2^-32
}

// ---------------- host -------------------------------------------------------
// ws layout: PK 524288 B | TL 524288 B | T01 262144 B   (total 1310720 B)
#define PK_OFF  0u
#define TL_OFF  524288u
#define T01_OFF 1048576u

extern "C" void kernel_launch(void* const* d_in, const int* in_sizes, int n_in,
                              void* d_out, int out_size, void* d_ws, size_t ws_size,
                              hipStream_t stream) {
    const int*   idx   = (const int*)d_in[0];    // (B, 8) int32
    const float* core0 = (const float*)d_in[1];  // (1, 64, 32)
    const float* mid   = (const float*)d_in[2];  // (6, 32, 64, 32)
    const float* lastc = (const float*)d_in[3];  // (32, 64, 1)
    float* out = (float*)d_out;

    __half2* PK  = (__half2*)((char*)d_ws + PK_OFF);
    float*   TL  = (float*)((char*)d_ws + TL_OFF);
    __half*  T01 = (__half*)((char*)d_ws + T01_OFF);

    hipLaunchKernelGGL(build_tables, dim3(393216 / 256), dim3(256), 0, stream,
                       core0, mid, lastc, PK, T01, TL);
    hipLaunchKernelGGL(tt_main, dim3((B_TOTAL * 8) / 256), dim3(256), 0, stream,
                       idx, T01, PK, TL, out);
}